// Round 3
// baseline (175.492 us; speedup 1.0000x reference)
//
#include <hip/hip_runtime.h>
#include <math.h>

// NetVLAD clustering layer, f32, MI355X.
// x:[16,256,1500], centroids:[64,256], lin_w:[66,256], lin_b:[66]
// out: [16, 64*256] f32
//
// R3: wave-granular GEMMs. Both GEMMs are tiny (~0.8 GFLOP each), so the
// scarce resource is WAVES, not FLOPs: per-wave time = 8*WT*WC*K cycles.
// Design: 64-thread (1-wave) blocks, 64x64 wave tile, 8x8 thread tile,
// K-vectorized ds_read_b128 (LDS stride 20 floats: 16B-aligned, conflict-free
// for row sets {g,g+8,...,g+56}). Split-K to reach ~768 waves (3 blocks/CU,
// ~3 SIMDs busy -> LDS pipe uncontended, VALU-bound per wave).
//  K1 : logits partials Lpart[ks<2][u][64][t]   (split-K over f, 128 each)
//  K1g: ghost logits    Lg[2][u][t]             (W rows 64,65 = 2KB, s_load-hot)
//  K1b: softmax(66) -> a[u][c][t]               (folds split-K reduce + bias)
//  K2 : partial[ks<12][u][c][f] = sum_{t chunk} a*x   (t-chunks of 128)
//  K3 : comp = sum partials - asum*centroid; intra-normalize
//  K4 : global L2 normalize

#define NU 16
#define NF 256
#define NT 1500
#define NC 64
#define EPSN 1e-12f
#define K2_KS 12      // t-chunks of 128 (12*128=1536 >= 1500)

// ---------------- K1: main logits, split-K=2 ----------------
// grid (24, 2, 16), block 64. Wave tile 64t x 64c, K=128 (f half).
__global__ __launch_bounds__(64) void k1_logits(
        const float* __restrict__ x, const float* __restrict__ lin_w,
        float* __restrict__ Lpart) {
    const int t0 = blockIdx.x * 64;
    const int ks = blockIdx.y;
    const int u  = blockIdx.z;
    const int l  = threadIdx.x;
    const int tg = l & 7, cg = l >> 3;

    __shared__ float Xs[64][20];   // [t][k] transposed tile, stride 20
    __shared__ float Ws[64][20];   // [c][k]

    float acc[8][8];
    #pragma unroll
    for (int i = 0; i < 8; ++i)
        #pragma unroll
        for (int j = 0; j < 8; ++j) acc[i][j] = 0.0f;

    const int tl = (t0 + l < NT) ? (t0 + l) : (NT - 1);   // clamp loads
    const float* xcol = x + u * NF * NT + tl;             // + f*NT
    const float* wrow = lin_w + l * NF + ks * 128;        // lane = c row (0..63)

    for (int ch = 0; ch < 8; ++ch) {                      // 8 chunks of 16 k
        const int kf = ks * 128 + ch * 16;
        float xv[16];
        #pragma unroll
        for (int fi = 0; fi < 16; ++fi) xv[fi] = xcol[(kf + fi) * NT]; // coalesced over t
        float4 wv[4];
        #pragma unroll
        for (int q = 0; q < 4; ++q) wv[q] = *(const float4*)(wrow + ch * 16 + q * 4);

        __syncthreads();   // previous chunk's reads done
        #pragma unroll
        for (int q = 0; q < 4; ++q) {
            *(float4*)&Xs[l][q * 4] = make_float4(xv[q*4], xv[q*4+1], xv[q*4+2], xv[q*4+3]);
            *(float4*)&Ws[l][q * 4] = wv[q];
        }
        __syncthreads();

        #pragma unroll
        for (int kq = 0; kq < 4; ++kq) {
            float4 xf[8], wf[8];
            #pragma unroll
            for (int i = 0; i < 8; ++i) xf[i] = *(const float4*)&Xs[tg + 8*i][kq*4];
            #pragma unroll
            for (int j = 0; j < 8; ++j) wf[j] = *(const float4*)&Ws[cg + 8*j][kq*4];
            #pragma unroll
            for (int i = 0; i < 8; ++i)
                #pragma unroll
                for (int j = 0; j < 8; ++j)
                    acc[i][j] += xf[i].x*wf[j].x + xf[i].y*wf[j].y
                               + xf[i].z*wf[j].z + xf[i].w*wf[j].w;
        }
    }

    // Lpart[ks][u][c][t]
    #pragma unroll
    for (int j = 0; j < 8; ++j) {
        float* lp = Lpart + ((ks * NU + u) * NC + cg + 8*j) * NT;
        #pragma unroll
        for (int i = 0; i < 8; ++i) {
            const int t = t0 + tg + 8*i;
            if (t < NT) lp[t] = acc[i][j];
        }
    }
}

// ---------------- K1g: ghost logits (c=64,65) ----------------
// grid (24, 16), block 64. W ghost rows = 2 KB -> scalar-cache-resident s_loads.
__global__ __launch_bounds__(64) void k1_ghost(
        const float* __restrict__ x, const float* __restrict__ lin_w,
        float* __restrict__ Lg) {
    const int t = blockIdx.x * 64 + threadIdx.x;
    const int u = blockIdx.y;
    const int tl = (t < NT) ? t : (NT - 1);
    const float* xcol = x + u * NF * NT + tl;
    const float* w0 = lin_w + 64 * NF;
    const float* w1 = lin_w + 65 * NF;
    float g0 = 0.0f, g1 = 0.0f;
    #pragma unroll 4
    for (int f = 0; f < NF; f += 4) {
        const float4 a = *(const float4*)(w0 + f);   // wave-uniform -> s_load
        const float4 b = *(const float4*)(w1 + f);
        const float x0 = xcol[f * NT], x1 = xcol[(f+1) * NT];
        const float x2 = xcol[(f+2) * NT], x3 = xcol[(f+3) * NT];
        g0 += a.x*x0 + a.y*x1 + a.z*x2 + a.w*x3;
        g1 += b.x*x0 + b.y*x1 + b.z*x2 + b.w*x3;
    }
    if (t < NT) {
        Lg[u * NT + t]            = g0;
        Lg[NU * NT + u * NT + t]  = g1;
    }
}

// ---------------- K1b: combine split-K, +bias, softmax(66), write a ----------
// grid (24, 16), block 64. lane = t.
__global__ __launch_bounds__(64) void k1b_softmax(
        const float* __restrict__ Lpart, const float* __restrict__ Lg,
        const float* __restrict__ lin_b, float* __restrict__ a_ws) {
    const int t = blockIdx.x * 64 + threadIdx.x;
    const int u = blockIdx.y;
    if (t >= NT) return;
    const float* L0 = Lpart + (0 * NU + u) * NC * NT + t;
    const float* L1 = Lpart + (1 * NU + u) * NC * NT + t;
    float v[NC];
    float m = -INFINITY;
    #pragma unroll
    for (int c = 0; c < NC; ++c) {
        v[c] = L0[c * NT] + L1[c * NT] + lin_b[c];   // lin_b: uniform -> s_load
        m = fmaxf(m, v[c]);
    }
    const float g0 = Lg[u * NT + t] + lin_b[64];
    const float g1 = Lg[NU * NT + u * NT + t] + lin_b[65];
    m = fmaxf(m, fmaxf(g0, g1));
    float s = __expf(g0 - m) + __expf(g1 - m);
    #pragma unroll
    for (int c = 0; c < NC; ++c) { v[c] = __expf(v[c] - m); s += v[c]; }
    const float inv = 1.0f / s;
    #pragma unroll
    for (int c = 0; c < NC; ++c)
        a_ws[(u * NC + c) * NT + t] = v[c] * inv;    // coalesced per c
}

// ---------------- K2: aggregation GEMM, split-K=12 ----------------
// grid (12, 4, 16): t-chunk, f-tile, u. block 64. Wave tile 64c x 64f, K=128 t.
// Both operands t-contiguous in global -> b128 staging, no transpose.
__global__ __launch_bounds__(64) void k2_agg(
        const float* __restrict__ x, const float* __restrict__ a_ws,
        float* __restrict__ partial) {
    const int ks = blockIdx.x, ft = blockIdx.y, u = blockIdx.z;
    const int l  = threadIdx.x;
    const int cg = l & 7, fg = l >> 3;
    const int r = l >> 2, q = l & 3;               // staging row/quad

    __shared__ float As[64][20], Xs[64][20];

    float acc[8][8];
    #pragma unroll
    for (int i = 0; i < 8; ++i)
        #pragma unroll
        for (int j = 0; j < 8; ++j) acc[i][j] = 0.0f;

    for (int ch = 0; ch < 8; ++ch) {
        const int k0 = ks * 128 + ch * 16;         // t offset
        float4 av[4], xv[4];
        if (k0 + 15 < NT) {
            #pragma unroll
            for (int s = 0; s < 4; ++s) {
                const int row = r + 16 * s;
                av[s] = *(const float4*)(a_ws + (u * NC + row) * NT + k0 + 4*q);
                xv[s] = *(const float4*)(x + (u * NF + ft * 64 + row) * NT + k0 + 4*q);
            }
        } else {
            #pragma unroll
            for (int s = 0; s < 4; ++s) {
                const int row = r + 16 * s;
                const float* ap = a_ws + (u * NC + row) * NT;
                const float* xp = x + (u * NF + ft * 64 + row) * NT;
                float va[4], vx[4];
                #pragma unroll
                for (int e = 0; e < 4; ++e) {
                    const int k = k0 + 4*q + e;
                    va[e] = (k < NT) ? ap[k] : 0.0f;
                    vx[e] = (k < NT) ? xp[k] : 0.0f;
                }
                av[s] = make_float4(va[0], va[1], va[2], va[3]);
                xv[s] = make_float4(vx[0], vx[1], vx[2], vx[3]);
            }
        }

        __syncthreads();
        #pragma unroll
        for (int s = 0; s < 4; ++s) {
            *(float4*)&As[r + 16*s][4*q] = av[s];
            *(float4*)&Xs[r + 16*s][4*q] = xv[s];
        }
        __syncthreads();

        #pragma unroll
        for (int kq = 0; kq < 4; ++kq) {
            float4 af[8], xf[8];
            #pragma unroll
            for (int i = 0; i < 8; ++i) af[i] = *(const float4*)&As[cg + 8*i][kq*4];
            #pragma unroll
            for (int j = 0; j < 8; ++j) xf[j] = *(const float4*)&Xs[fg + 8*j][kq*4];
            #pragma unroll
            for (int i = 0; i < 8; ++i)
                #pragma unroll
                for (int j = 0; j < 8; ++j)
                    acc[i][j] += af[i].x*xf[j].x + af[i].y*xf[j].y
                               + af[i].z*xf[j].z + af[i].w*xf[j].w;
        }
    }

    // partial[ks][u][c][f]
    #pragma unroll
    for (int i = 0; i < 8; ++i) {
        float* op = partial + ((ks * NU + u) * NC + cg + 8*i) * NF + ft * 64;
        #pragma unroll
        for (int j = 0; j < 8; ++j) op[fg + 8*j] = acc[i][j];
    }
}

// ---------------- helpers ----------------
__device__ __forceinline__ float blk_reduce_sum(float v, float* sbuf) {
    #pragma unroll
    for (int off = 32; off > 0; off >>= 1) v += __shfl_down(v, off, 64);
    const int lane = threadIdx.x & 63, wv = threadIdx.x >> 6;
    if (lane == 0) sbuf[wv] = v;
    __syncthreads();
    float r = sbuf[0] + sbuf[1] + sbuf[2] + sbuf[3];
    __syncthreads();
    return r;
}

// ---------------- K3: reduce partials, centroid term, intra-norm -------------
// grid (64, 16), block 256 (one thread per f).
__global__ __launch_bounds__(256) void k3_norm(
        const float* __restrict__ a_ws, const float* __restrict__ partial,
        const float* __restrict__ centroids, float* __restrict__ compn,
        float* __restrict__ rowsq) {
    const int c = blockIdx.x, u = blockIdx.y;
    const int tid = threadIdx.x;
    __shared__ float sbuf[4];

    float s = 0.0f;
    const float* arow = a_ws + (u * NC + c) * NT;
    for (int i = tid; i < NT; i += 256) s += arow[i];
    const float asum = blk_reduce_sum(s, sbuf);

    float val = 0.0f;
    #pragma unroll
    for (int ks = 0; ks < K2_KS; ++ks)
        val += partial[((ks * NU + u) * NC + c) * NF + tid];
    val -= asum * centroids[c * NF + tid];

    const float ss = blk_reduce_sum(val * val, sbuf);
    const float d  = fmaxf(sqrtf(ss), EPSN);
    compn[(u * NC + c) * NF + tid] = val / d;
    if (tid == 0) rowsq[u * NC + c] = ss / (d * d);
}

// ---------------- K4: global normalize ----------------
// grid (4, 16), block 256.
__global__ __launch_bounds__(256) void k4_scale(
        const float* __restrict__ compn, const float* __restrict__ rowsq,
        float* __restrict__ out) {
    const int u = blockIdx.y;
    const int tid = threadIdx.x;
    float gss = 0.0f;
    #pragma unroll
    for (int cc = 0; cc < NC; ++cc) gss += rowsq[u * NC + cc];  // uniform
    const float inv = 1.0f / fmaxf(sqrtf(gss), EPSN);
    const int base = u * (NC * NF) + blockIdx.x * 4096;
    #pragma unroll
    for (int r = 0; r < 16; ++r) {
        const int idx = base + r * 256 + tid;
        out[idx] = compn[idx] * inv;
    }
}

// ---------------- launcher ----------------
extern "C" void kernel_launch(void* const* d_in, const int* in_sizes, int n_in,
                              void* d_out, int out_size, void* d_ws, size_t ws_size,
                              hipStream_t stream) {
    (void)in_sizes; (void)n_in; (void)out_size; (void)ws_size;
    const float* x         = (const float*)d_in[0];
    const float* centroids = (const float*)d_in[1];
    const float* lin_w     = (const float*)d_in[2];
    const float* lin_b     = (const float*)d_in[3];
    float* out = (float*)d_out;

    float* ws      = (float*)d_ws;
    float* Lpart   = ws;                                   // 2*16*64*1500 = 3,072,000
    float* Lg      = Lpart + 2 * NU * NC * NT;             // 2*16*1500   = 48,000
    float* a_ws    = Lg + 2 * NU * NT;                     // 16*64*1500  = 1,536,000
    float* partial = a_ws + NU * NC * NT;                  // 12*16*64*256= 3,145,728
    float* compn   = partial + K2_KS * NU * NC * NF;       // 262,144
    float* rowsq   = compn + NU * NC * NF;                 // 1,024  (~32 MB total)

    hipLaunchKernelGGL(k1_logits,   dim3(24, 2, NU),      dim3(64), 0, stream, x, lin_w, Lpart);
    hipLaunchKernelGGL(k1_ghost,    dim3(24, NU),         dim3(64), 0, stream, x, lin_w, Lg);
    hipLaunchKernelGGL(k1b_softmax, dim3(24, NU),         dim3(64), 0, stream, Lpart, Lg, lin_b, a_ws);
    hipLaunchKernelGGL(k2_agg,      dim3(K2_KS, 4, NU),   dim3(64), 0, stream, x, a_ws, partial);
    hipLaunchKernelGGL(k3_norm,     dim3(NC, NU),         dim3(256), 0, stream, a_ws, partial, centroids, compn, rowsq);
    hipLaunchKernelGGL(k4_scale,    dim3(4, NU),          dim3(256), 0, stream, compn, rowsq, out);
}

// Round 4
// 155.130 us; speedup vs baseline: 1.1313x; 1.1313x over previous
//
#include <hip/hip_runtime.h>
#include <math.h>

// NetVLAD clustering layer, f32, MI355X.
// x:[16,256,1500], centroids:[64,256], lin_w:[66,256], lin_b:[66]
// out: [16, 64*256] f32
//
// R4: 4 kernels, all 256-thread blocks, >=6 waves/CU where possible.
// Broadcast operands (W, a) read via LDS same-address b128 broadcast,
// amortized over 4-wide register tiles (Tt/Tf=4) so LDS-instr:FMA <= 1:12.
// x read coalesced (direct global in K1; LDS-staged in K2f).
// Softmax fused into the aggregation kernel: 'a' never hits HBM.
//
//  K1 : Lpart[ks<2][u][c<66][t] = x(f-half ks) . W   (logit partials)
//  K2f: softmax(sum Lpart + b) -> a (LDS only) -> partial[ks12][u][c][f],
//       asum_part[ks12][u][c]
//  K3 : comp = sum partial - asum*centroid; intra-normalize (per u,c)
//  K4 : global L2 normalize per u

#define NU 16
#define NF 256
#define NT 1500
#define NT_PAD 1536
#define NC 64
#define NCG 66
#define EPSN 1e-12f
#define K2_KS 12      // t-chunks of 128 (12*128 = 1536)

// ---------------- K1: logit partials ----------------
// grid (16 u, 12 tt, 2 ks), block 256 = 4 waves.
// Block: 128 t x 66 c x 128 k(f). Waves c-split (rows w+4i), Tt=2.
// W staged once in LDS (34.8 KB), read as same-address b128 broadcast.
// x read straight from global, coalesced over t (L2 serves the 4x reuse).
__global__ __launch_bounds__(256) void k1_logits(
        const float* __restrict__ x, const float* __restrict__ lin_w,
        float* __restrict__ Lpart) {
    const int u  = blockIdx.x;
    const int t0 = blockIdx.y * 128;
    const int ks = blockIdx.z;
    const int tid  = threadIdx.x;
    const int lane = tid & 63;
    const int w    = tid >> 6;

    __shared__ float Ws[NCG][132];   // rows 528B (16B-aligned), broadcast reads

    for (int idx = tid; idx < NCG * 128; idx += 256) {
        const int c = idx >> 7, k = idx & 127;
        Ws[c][k] = lin_w[c * NF + ks * 128 + k];
    }
    __syncthreads();

    const int ta = t0 + lane, tb = t0 + 64 + lane;
    const int ca = (ta < NT) ? ta : (NT - 1);
    const int cb = (tb < NT) ? tb : (NT - 1);
    const float* xb = x + (u * NF + ks * 128) * NT;

    float acc[17][2];
    #pragma unroll
    for (int i = 0; i < 17; ++i) { acc[i][0] = 0.0f; acc[i][1] = 0.0f; }

    #pragma unroll 2
    for (int kq = 0; kq < 32; ++kq) {
        float xa[4], xv[4];
        #pragma unroll
        for (int e = 0; e < 4; ++e) {
            xa[e] = xb[(kq * 4 + e) * NT + ca];   // coalesced over t
            xv[e] = xb[(kq * 4 + e) * NT + cb];
        }
        #pragma unroll
        for (int i = 0; i < 17; ++i) {
            const int cc = (w + 4 * i < NCG) ? (w + 4 * i) : (NCG - 1);
            const float4 wv = *(const float4*)&Ws[cc][kq * 4];   // broadcast
            acc[i][0] += wv.x * xa[0] + wv.y * xa[1] + wv.z * xa[2] + wv.w * xa[3];
            acc[i][1] += wv.x * xv[0] + wv.y * xv[1] + wv.z * xv[2] + wv.w * xv[3];
        }
    }

    #pragma unroll
    for (int i = 0; i < 17; ++i) {
        const int c = w + 4 * i;
        if (c < NCG) {
            float* lp = Lpart + ((ks * NU + u) * NCG + c) * NT_PAD + t0;
            lp[lane]      = acc[i][0];     // t >= NT rows hold dups; ignored later
            lp[64 + lane] = acc[i][1];
        }
    }
}

// ---------------- K2f: softmax + aggregation partials ----------------
// grid (16 u, 12 ks), block 256 = 4 waves. t-chunk 128.
// Phase A: threads 0-127 softmax their t (a -> LDS As, zero for t>=NT);
//          threads 128-255 stage x chunk 0.
// GEMM: 64c x 256f x 128k; waves c-split 16; lane f = lane+64j (Tf=4);
// a via As broadcast b128, x via Xs (stride 20, b128), register prefetch.
__global__ __launch_bounds__(256) void k2_fused(
        const float* __restrict__ x, const float* __restrict__ Lpart,
        const float* __restrict__ lin_b, float* __restrict__ partial,
        float* __restrict__ asum_part) {
    const int u  = blockIdx.x;
    const int ks = blockIdx.y;
    const int t0 = ks * 128;
    const int tid  = threadIdx.x;
    const int lane = tid & 63;
    const int w    = tid >> 6;

    __shared__ float As[NC][132];     // a[c][t_local], rows 528B
    __shared__ float Xs[NF][20];      // x[f][k_local 16], rows 80B

    if (tid < 128) {
        const int t = t0 + tid;
        if (t < NT) {
            float a[NCG];
            float m = -INFINITY;
            #pragma unroll
            for (int c = 0; c < NCG; ++c) {
                const float v = Lpart[((0 * NU + u) * NCG + c) * NT_PAD + t]
                              + Lpart[((1 * NU + u) * NCG + c) * NT_PAD + t]
                              + lin_b[c];
                a[c] = v;
                m = fmaxf(m, v);
            }
            float s = 0.0f;
            #pragma unroll
            for (int c = 0; c < NCG; ++c) { a[c] = __expf(a[c] - m); s += a[c]; }
            const float inv = 1.0f / s;
            #pragma unroll
            for (int c = 0; c < NC; ++c) As[c][tid] = a[c] * inv;
        } else {
            #pragma unroll
            for (int c = 0; c < NC; ++c) As[c][tid] = 0.0f;
        }
    } else {
        const int tl = tid - 128;
        #pragma unroll
        for (int p = 0; p < 8; ++p) {               // chunk 0: 1024 float4s
            const int idx = p * 128 + tl;
            const int f = idx >> 2, kq = idx & 3;
            const int k = t0 + kq * 4;              // <= 1423, always in-bounds
            *(float4*)&Xs[f][kq * 4] = *(const float4*)(x + (u * NF + f) * NT + k);
        }
    }
    __syncthreads();

    const int c0 = w * 16;
    float acc[16][4];
    #pragma unroll
    for (int i = 0; i < 16; ++i)
        #pragma unroll
        for (int j = 0; j < 4; ++j) acc[i][j] = 0.0f;

    for (int sc = 0; sc < 8; ++sc) {
        float4 pf[4];
        if (sc < 7) {                                // register-prefetch chunk sc+1
            #pragma unroll
            for (int p = 0; p < 4; ++p) {
                const int idx = p * 256 + tid;
                const int f = idx >> 2;
                int k = t0 + (sc + 1) * 16 + (idx & 3) * 4;
                if (k > NT - 4) k = NT - 4;          // clamp (a=0 kills garbage)
                pf[p] = *(const float4*)(x + (u * NF + f) * NT + k);
            }
        }

        #pragma unroll
        for (int kq = 0; kq < 4; ++kq) {
            float4 xf[4];
            #pragma unroll
            for (int j = 0; j < 4; ++j)
                xf[j] = *(const float4*)&Xs[lane + 64 * j][kq * 4];
            #pragma unroll
            for (int i = 0; i < 16; ++i) {
                const float4 av = *(const float4*)&As[c0 + i][sc * 16 + kq * 4];
                #pragma unroll
                for (int j = 0; j < 4; ++j)
                    acc[i][j] += av.x * xf[j].x + av.y * xf[j].y
                               + av.z * xf[j].z + av.w * xf[j].w;
            }
        }
        __syncthreads();
        if (sc < 7) {
            #pragma unroll
            for (int p = 0; p < 4; ++p) {
                const int idx = p * 256 + tid;
                *(float4*)&Xs[idx >> 2][(idx & 3) * 4] = pf[p];
            }
            __syncthreads();
        }
    }

    // partial[ks][u][c][f]
    #pragma unroll
    for (int i = 0; i < 16; ++i) {
        float* op = partial + ((ks * NU + u) * NC + c0 + i) * NF;
        #pragma unroll
        for (int j = 0; j < 4; ++j) op[lane + 64 * j] = acc[i][j];
    }

    // asum partials: per wave, its 16 c rows; lane-parallel over t + shuffle
    #pragma unroll
    for (int i = 0; i < 16; ++i) {
        float s = As[c0 + i][lane] + As[c0 + i][64 + lane];
        #pragma unroll
        for (int off = 32; off > 0; off >>= 1) s += __shfl_down(s, off, 64);
        if (lane == 0) asum_part[(ks * NU + u) * NC + c0 + i] = s;
    }
}

// ---------------- K3: combine partials, centroid term, intra-norm ------------
// grid (64 c, 16 u), block 256 (thread = f).
__global__ __launch_bounds__(256) void k3_norm(
        const float* __restrict__ partial, const float* __restrict__ asum_part,
        const float* __restrict__ centroids, float* __restrict__ compn,
        float* __restrict__ rowsq) {
    const int c = blockIdx.x, u = blockIdx.y;
    const int tid = threadIdx.x;
    __shared__ float sbuf[4];

    float asum = 0.0f;
    #pragma unroll
    for (int ks = 0; ks < K2_KS; ++ks)
        asum += asum_part[(ks * NU + u) * NC + c];   // uniform -> s_load

    float val = 0.0f;
    #pragma unroll
    for (int ks = 0; ks < K2_KS; ++ks)
        val += partial[((ks * NU + u) * NC + c) * NF + tid];
    val -= asum * centroids[c * NF + tid];

    float v = val * val;
    #pragma unroll
    for (int off = 32; off > 0; off >>= 1) v += __shfl_down(v, off, 64);
    if ((tid & 63) == 0) sbuf[tid >> 6] = v;
    __syncthreads();
    const float ss = sbuf[0] + sbuf[1] + sbuf[2] + sbuf[3];

    const float d = fmaxf(sqrtf(ss), EPSN);
    compn[(u * NC + c) * NF + tid] = val / d;
    if (tid == 0) rowsq[u * NC + c] = ss / (d * d);
}

// ---------------- K4: global normalize ----------------
// grid (4, 16), block 256.
__global__ __launch_bounds__(256) void k4_scale(
        const float* __restrict__ compn, const float* __restrict__ rowsq,
        float* __restrict__ out) {
    const int u = blockIdx.y;
    const int tid = threadIdx.x;
    float gss = 0.0f;
    #pragma unroll
    for (int cc = 0; cc < NC; ++cc) gss += rowsq[u * NC + cc];  // uniform
    const float inv = 1.0f / fmaxf(sqrtf(gss), EPSN);
    const int base = u * (NC * NF) + blockIdx.x * 4096;
    #pragma unroll
    for (int r = 0; r < 16; ++r) {
        const int idx = base + r * 256 + tid;
        out[idx] = compn[idx] * inv;
    }
}

// ---------------- launcher ----------------
extern "C" void kernel_launch(void* const* d_in, const int* in_sizes, int n_in,
                              void* d_out, int out_size, void* d_ws, size_t ws_size,
                              hipStream_t stream) {
    (void)in_sizes; (void)n_in; (void)out_size; (void)ws_size;
    const float* x         = (const float*)d_in[0];
    const float* centroids = (const float*)d_in[1];
    const float* lin_w     = (const float*)d_in[2];
    const float* lin_b     = (const float*)d_in[3];
    float* out = (float*)d_out;

    float* ws        = (float*)d_ws;
    float* Lpart     = ws;                                 // 2*16*66*1536 = 3,244,032
    float* partial   = Lpart + 2 * NU * NCG * NT_PAD;      // 12*16*64*256 = 3,145,728
    float* asum_part = partial + K2_KS * NU * NC * NF;     // 12*16*64     = 12,288
    float* compn     = asum_part + K2_KS * NU * NC;        // 262,144
    float* rowsq     = compn + NU * NC * NF;               // 1,024   (~26.7 MB)

    hipLaunchKernelGGL(k1_logits, dim3(NU, 12, 2), dim3(256), 0, stream, x, lin_w, Lpart);
    hipLaunchKernelGGL(k2_fused,  dim3(NU, K2_KS), dim3(256), 0, stream, x, Lpart, lin_b, partial, asum_part);
    hipLaunchKernelGGL(k3_norm,   dim3(NC, NU),    dim3(256), 0, stream, partial, asum_part, centroids, compn, rowsq);
    hipLaunchKernelGGL(k4_scale,  dim3(4, NU),     dim3(256), 0, stream, compn, rowsq, out);
}